// Round 4
// baseline (292.210 us; speedup 1.0000x reference)
//
#include <hip/hip_runtime.h>
#include <math.h>

// Problem constants (fixed by the reference): ip (8, 256, 128, 128) fp32.
#define NB   8
#define NC   256
#define NHW  (128 * 128)

// Out[c,p] = sum_k M[c,k] X[k,p], M = 256x256 DCT-III matrix.
// Symmetry: M[255-c][k] = (-1)^k M[c][k] -> store rows c=0..127 only (64 KB bf16);
// mirror half computed with sign-flipped-odd-k X fragments (XOR bit 31 per dword).
//
// Structure: NO LDS, NO barriers. Block = 256 threads = 4 waves; block tile =
// 256 out-c x 32 p; wave = one 32-row stored-c strip (x2 mirror) x 32 p.
// A frags: global dwordx4, 16 B contiguous per lane (coef already bf16, L1/L2-hot).
// B frags: global dword per lane (16-lane 64-B segments), identical across the
// block's 4 waves -> L1 reuse. Occupancy VGPR-bound (~16 waves/CU), every wave
// an independent MFMA pipeline -> latency hidden by TLP, not by barriers.

typedef __attribute__((ext_vector_type(4))) float f32x4;
typedef __attribute__((ext_vector_type(8))) short bf16x8;
typedef __attribute__((ext_vector_type(4))) unsigned int u32x4;

__device__ __forceinline__ unsigned short f2bf(float f) {
    unsigned u = __builtin_bit_cast(unsigned, f);
    u += 0x7fffu + ((u >> 16) & 1u);
    return (unsigned short)(u >> 16);
}

__device__ __forceinline__ unsigned pack2bf(float a, float b) {
    unsigned lo = __builtin_bit_cast(unsigned, a);
    lo += 0x7fffu + ((lo >> 16) & 1u);
    unsigned hi = __builtin_bit_cast(unsigned, b);
    hi += 0x7fffu + ((hi >> 16) & 1u);
    return (lo >> 16) | (hi & 0xffff0000u);
}

// Flip sign of odd-k bf16 elements: dword = (even k | odd k << 16) -> XOR bit 31.
__device__ __forceinline__ bf16x8 flip_odd(bf16x8 b) {
    u32x4 u = __builtin_bit_cast(u32x4, b);
    u ^= (u32x4){0x80000000u, 0x80000000u, 0x80000000u, 0x80000000u};
    return __builtin_bit_cast(bf16x8, u);
}

// DCT-III coefficients, rows c = 0..127 only. M[c][k] = (k==0)?1:2cos(pi*k*(2c+1)/512).
__global__ void coef_kernel(unsigned short* __restrict__ coef) {
    int idx = blockIdx.x * 256 + threadIdx.x;     // 0..32767
    int c = idx >> 8;
    int k = idx & 255;
    int t = (k * (2 * c + 1)) & 1023;
    float v = (k == 0) ? 1.0f : 2.0f * cosf((float)t * (float)(M_PI / 512.0));
    coef[idx] = f2bf(v);
}

__global__ __launch_bounds__(256, 4)
void dct_gemm(const float* __restrict__ X, const unsigned short* __restrict__ Mcoef,
              float* __restrict__ Out) {
    const int tid  = threadIdx.x;
    const int lane = tid & 63;
    const int wave = tid >> 6;        // 0..3: 32-row stored-c strip
    const int m16  = lane & 15;
    const int quad = lane >> 4;

    const int p0 = blockIdx.x * 32;
    const size_t base = (size_t)blockIdx.y * (NC * NHW);
    const float* Xb = X + base + p0;
    float* Ob = Out + base + p0;

    // A fragment rows: wave*32 + mt*16 + m16; lane's 16 B = k quad*8..quad*8+7
    const unsigned short* aP0 = Mcoef + (wave * 32 + m16) * NC + quad * 8;
    const unsigned short* aP1 = aP0 + 16 * NC;

    // B: lane reads X[kb + quad*8 + j][p0 + nt*16 + m16]
    const float* bP = Xb + (size_t)(quad * 8) * NHW + m16;

    f32x4 acc[2][2][2];
#pragma unroll
    for (int a = 0; a < 2; a++)
#pragma unroll
        for (int b = 0; b < 2; b++)
#pragma unroll
            for (int h = 0; h < 2; h++) acc[a][b][h] = (f32x4){0.f, 0.f, 0.f, 0.f};

#pragma unroll
    for (int kk = 0; kk < 8; kk++) {
        const int kb = kk * 32;

        bf16x8 af0 = *(const bf16x8*)(aP0 + kb);   // global dwordx4, L1/L2-hot
        bf16x8 af1 = *(const bf16x8*)(aP1 + kb);

        float fb[2][8];
#pragma unroll
        for (int nt = 0; nt < 2; nt++)
#pragma unroll
            for (int j = 0; j < 8; j++)
                fb[nt][j] = bP[(size_t)(kb + j) * NHW + nt * 16];

        bf16x8 bf[2], bn[2];
#pragma unroll
        for (int nt = 0; nt < 2; nt++) {
            u32x4 pk;
#pragma unroll
            for (int j = 0; j < 4; j++)
                pk[j] = pack2bf(fb[nt][2 * j], fb[nt][2 * j + 1]);
            bf[nt] = __builtin_bit_cast(bf16x8, pk);
            bn[nt] = flip_odd(bf[nt]);
        }

        acc[0][0][0] = __builtin_amdgcn_mfma_f32_16x16x32_bf16(af0, bf[0], acc[0][0][0], 0, 0, 0);
        acc[0][1][0] = __builtin_amdgcn_mfma_f32_16x16x32_bf16(af0, bf[1], acc[0][1][0], 0, 0, 0);
        acc[1][0][0] = __builtin_amdgcn_mfma_f32_16x16x32_bf16(af1, bf[0], acc[1][0][0], 0, 0, 0);
        acc[1][1][0] = __builtin_amdgcn_mfma_f32_16x16x32_bf16(af1, bf[1], acc[1][1][0], 0, 0, 0);
        acc[0][0][1] = __builtin_amdgcn_mfma_f32_16x16x32_bf16(af0, bn[0], acc[0][0][1], 0, 0, 0);
        acc[0][1][1] = __builtin_amdgcn_mfma_f32_16x16x32_bf16(af0, bn[1], acc[0][1][1], 0, 0, 0);
        acc[1][0][1] = __builtin_amdgcn_mfma_f32_16x16x32_bf16(af1, bn[0], acc[1][0][1], 0, 0, 0);
        acc[1][1][1] = __builtin_amdgcn_mfma_f32_16x16x32_bf16(af1, bn[1], acc[1][1][1], 0, 0, 0);
    }

    // ---- store: D col(p) = lane&15, row(c) = quad*4 + r. lo half row cS,
    //      mirror half row 255-cS. 32 dword stores, 64-B segments. ----
#pragma unroll
    for (int mt = 0; mt < 2; mt++) {
        const int cS = wave * 32 + mt * 16 + quad * 4;
#pragma unroll
        for (int nt = 0; nt < 2; nt++) {
            float* o = Ob + nt * 16 + m16;
#pragma unroll
            for (int r = 0; r < 4; r++) {
                o[(size_t)(cS + r) * NHW]       = acc[mt][nt][0][r];
                o[(size_t)(255 - cS - r) * NHW] = acc[mt][nt][1][r];
            }
        }
    }
}

extern "C" void kernel_launch(void* const* d_in, const int* in_sizes, int n_in,
                              void* d_out, int out_size, void* d_ws, size_t ws_size,
                              hipStream_t stream) {
    const float* ip = (const float*)d_in[0];
    float* out = (float*)d_out;
    unsigned short* coef = (unsigned short*)d_ws;   // 128*256*2 = 64 KB of scratch

    // must redo every launch: d_ws is re-poisoned before each timed call
    coef_kernel<<<dim3(128), dim3(256), 0, stream>>>(coef);

    // 4096 independent blocks, one 256c x 32p tile each; no LDS, no barriers.
    dct_gemm<<<dim3(NHW / 32, NB), dim3(256), 0, stream>>>(ip, coef, out);
}

// Round 5
// 242.713 us; speedup vs baseline: 1.2039x; 1.2039x over previous
//
#include <hip/hip_runtime.h>
#include <math.h>

// Problem constants (fixed by the reference): ip (8, 256, 128, 128) fp32.
#define NB   8
#define NC   256
#define NHW  (128 * 128)

// Out[c,p] = sum_k M[c,k] X[k,p], M = 256x256 DCT-III matrix.
// Symmetry: M[255-c][k] = (-1)^k M[c][k] -> store rows c=0..127 only (bf16);
// mirror half via sign-flipped odd-k X fragments (XOR bit 31 per dword).
//
// Structure (round-2 schedule, shrunk for TLP): block = 256 thr = 4 waves,
// tile = 256 out-c x 32 p, BK=64, 4 k-steps. LDS = A dbuf 2x16KB + X dbuf
// 2x4KB = 40 KB -> 4 blocks/CU resident (4 staggered barrier domains per CU
// fill each other's vmcnt-drain gaps). Wave = 32 stored-c strip x 32 p,
// acc[2][2][2] = 32 regs. One barrier per k-step, depth-1 prefetch.

#define BK 64
#define NITER (NC / BK)       // 4
#define ABUF 16384            // A buffers at 0, 16384   (128 rows x 128 B)
#define XLDS 32768            // X buffers at 32768, 36864 (32 rows x 128 B)
#define XBUF 4096

typedef __attribute__((ext_vector_type(4))) float f32x4;
typedef __attribute__((ext_vector_type(8))) short bf16x8;
typedef __attribute__((ext_vector_type(4))) unsigned int u32x4;

__device__ __forceinline__ unsigned short f2bf(float f) {
    unsigned u = __builtin_bit_cast(unsigned, f);
    u += 0x7fffu + ((u >> 16) & 1u);
    return (unsigned short)(u >> 16);
}

__device__ __forceinline__ unsigned pack2bf(float a, float b) {
    unsigned lo = __builtin_bit_cast(unsigned, a);
    lo += 0x7fffu + ((lo >> 16) & 1u);
    unsigned hi = __builtin_bit_cast(unsigned, b);
    hi += 0x7fffu + ((hi >> 16) & 1u);
    return (lo >> 16) | (hi & 0xffff0000u);
}

// Flip sign of odd-k bf16 elements: dword = (even k | odd k << 16) -> XOR bit 31.
__device__ __forceinline__ bf16x8 flip_odd(bf16x8 b) {
    u32x4 u = __builtin_bit_cast(u32x4, b);
    u ^= (u32x4){0x80000000u, 0x80000000u, 0x80000000u, 0x80000000u};
    return __builtin_bit_cast(bf16x8, u);
}

// DCT-III coefficients, rows c = 0..127 only. M[c][k] = (k==0)?1:2cos(pi*k*(2c+1)/512).
__global__ void coef_kernel(unsigned short* __restrict__ coef) {
    int idx = blockIdx.x * 256 + threadIdx.x;     // 0..32767
    int c = idx >> 8;
    int k = idx & 255;
    int t = (k * (2 * c + 1)) & 1023;
    float v = (k == 0) ? 1.0f : 2.0f * cosf((float)t * (float)(M_PI / 512.0));
    coef[idx] = f2bf(v);
}

__device__ __forceinline__ void gload_lds16(const void* g, void* l) {
    __builtin_amdgcn_global_load_lds(
        (const __attribute__((address_space(1))) unsigned int*)g,
        (__attribute__((address_space(3))) unsigned int*)l,
        16, 0, 0);
}

// LDS rows are 128 B (64 bf16 = one BK window), 8 16-B slots/row.
// Logical slot s of row r stored at s ^ (r & 7) -> all b128 ops <=2-way (free).

__global__ __launch_bounds__(256, 4)
void dct_gemm(const float* __restrict__ X, const unsigned short* __restrict__ Mcoef,
              float* __restrict__ Out) {
    __shared__ __align__(16) unsigned char lds[40960];

    const int tid  = threadIdx.x;
    const int lane = tid & 63;
    const int wave = tid >> 6;        // 0..3: 32-row stored-c strip
    const int m16  = lane & 15;
    const int quad = lane >> 4;

    const int p0 = blockIdx.x * 32;
    const size_t base = (size_t)blockIdx.y * (NC * NHW);
    const float* Xg = X + base;
    float* Ob = Out + base + p0;

    // ---- A staging (global_load_lds, linear dest, pre-swizzled source) ----
    // instr i: dest L = i*4096 + tid*16 -> row = i*32 + tid/8, dslot = tid&7.
    // logical slot at this dest = (tid&7) ^ (row&7) = (tid&7) ^ ((tid>>3)&7).
    const int aRowT = tid >> 3;                       // 0..31 (row within i-strip)
    const int aSlot = (tid & 7) ^ (aRowT & 7);        // same for all i
    const unsigned short* aS = Mcoef + aRowT * NC + aSlot * 8;
    const int aDst = tid * 16;

    // ---- X staging: p = tid&31, k-group g = tid>>5 (k = g*8..g*8+7) ----
    const int sp = tid & 31;
    const int g  = tid >> 5;
    const float* xS = Xg + (size_t)(g * 8) * NHW + p0 + sp;
    const int xWoff = sp * 128 + (((g ^ (sp & 7)) & 7) << 4);

    f32x4 acc[2][2][2];
#pragma unroll
    for (int a = 0; a < 2; a++)
#pragma unroll
        for (int b = 0; b < 2; b++)
#pragma unroll
            for (int h = 0; h < 2; h++) acc[a][b][h] = (f32x4){0.f, 0.f, 0.f, 0.f};

    // ---- prologue: stage k-step 0 into buf 0 ----
    {
        float v[8];
#pragma unroll
        for (int j = 0; j < 8; j++) v[j] = xS[(size_t)j * NHW];
#pragma unroll
        for (int i = 0; i < 4; i++)
            gload_lds16(aS + i * 32 * NC, lds + i * 4096 + aDst);
        int4 q = { (int)pack2bf(v[0], v[1]), (int)pack2bf(v[2], v[3]),
                   (int)pack2bf(v[4], v[5]), (int)pack2bf(v[6], v[7]) };
        *(int4*)(lds + XLDS + xWoff) = q;
    }
    __syncthreads();

    const int aB = (wave * 32 + m16) * 128;   // A frag row base (mt adds 16*128)
    const int xB = m16 * 128;                 // X frag row base (nt adds 16*128)
    const int rs = m16 & 7;                   // row-swizzle key for frag reads

    for (int t = 0; t < NITER; t++) {
        const int cb = t & 1;
        const unsigned char* Ac = lds + cb * ABUF;
        const unsigned char* Xc = lds + XLDS + cb * XBUF;

        // depth-1 prefetch: X to regs, A via async gload into the other buffer
        float v[8];
        if (t + 1 < NITER) {
            const int k1 = (t + 1) * BK;
#pragma unroll
            for (int j = 0; j < 8; j++) v[j] = xS[(size_t)(k1 + j) * NHW];
#pragma unroll
            for (int i = 0; i < 4; i++)
                gload_lds16(aS + i * 32 * NC + k1, lds + (cb ^ 1) * ABUF + i * 4096 + aDst);
        }

#pragma unroll
        for (int kk = 0; kk < 2; kk++) {
            const int so = (((kk * 4 + quad) ^ rs) << 4);
            bf16x8 af0 = *(const bf16x8*)(Ac + aB + so);
            bf16x8 af1 = *(const bf16x8*)(Ac + aB + 16 * 128 + so);
            bf16x8 bf0 = *(const bf16x8*)(Xc + xB + so);
            bf16x8 bf1 = *(const bf16x8*)(Xc + xB + 16 * 128 + so);
            bf16x8 bn0 = flip_odd(bf0);
            bf16x8 bn1 = flip_odd(bf1);
            acc[0][0][0] = __builtin_amdgcn_mfma_f32_16x16x32_bf16(af0, bf0, acc[0][0][0], 0, 0, 0);
            acc[0][1][0] = __builtin_amdgcn_mfma_f32_16x16x32_bf16(af0, bf1, acc[0][1][0], 0, 0, 0);
            acc[1][0][0] = __builtin_amdgcn_mfma_f32_16x16x32_bf16(af1, bf0, acc[1][0][0], 0, 0, 0);
            acc[1][1][0] = __builtin_amdgcn_mfma_f32_16x16x32_bf16(af1, bf1, acc[1][1][0], 0, 0, 0);
            acc[0][0][1] = __builtin_amdgcn_mfma_f32_16x16x32_bf16(af0, bn0, acc[0][0][1], 0, 0, 0);
            acc[0][1][1] = __builtin_amdgcn_mfma_f32_16x16x32_bf16(af0, bn1, acc[0][1][1], 0, 0, 0);
            acc[1][0][1] = __builtin_amdgcn_mfma_f32_16x16x32_bf16(af1, bn0, acc[1][0][1], 0, 0, 0);
            acc[1][1][1] = __builtin_amdgcn_mfma_f32_16x16x32_bf16(af1, bn1, acc[1][1][1], 0, 0, 0);
        }

        if (t + 1 < NITER) {
            // stage X t+1 into the other buffer (its readers finished before
            // the previous barrier), then ONE barrier (drains A gloads too).
            int4 q = { (int)pack2bf(v[0], v[1]), (int)pack2bf(v[2], v[3]),
                       (int)pack2bf(v[4], v[5]), (int)pack2bf(v[6], v[7]) };
            *(int4*)(lds + XLDS + (cb ^ 1) * XBUF + xWoff) = q;
            __syncthreads();
        }
    }

    // ---- store: D col(p) = lane&15, row(c) = quad*4 + r. lo half row cS,
    //      mirror half row 255-cS. ----
#pragma unroll
    for (int mt = 0; mt < 2; mt++) {
        const int cS = wave * 32 + mt * 16 + quad * 4;
#pragma unroll
        for (int nt = 0; nt < 2; nt++) {
            float* o = Ob + nt * 16 + m16;
#pragma unroll
            for (int r = 0; r < 4; r++) {
                o[(size_t)(cS + r) * NHW]       = acc[mt][nt][0][r];
                o[(size_t)(255 - cS - r) * NHW] = acc[mt][nt][1][r];
            }
        }
    }
}

extern "C" void kernel_launch(void* const* d_in, const int* in_sizes, int n_in,
                              void* d_out, int out_size, void* d_ws, size_t ws_size,
                              hipStream_t stream) {
    const float* ip = (const float*)d_in[0];
    float* out = (float*)d_out;
    unsigned short* coef = (unsigned short*)d_ws;   // 128*256*2 = 64 KB of scratch

    // must redo every launch: d_ws is re-poisoned before each timed call
    coef_kernel<<<dim3(128), dim3(256), 0, stream>>>(coef);

    // 4096 blocks (512 p-tiles x 8 batches), 256 threads, 40 KB LDS each.
    dct_gemm<<<dim3(NHW / 32, NB), dim3(256), 0, stream>>>(ip, coef, out);
}